// Round 13
// baseline (604.595 us; speedup 1.0000x reference)
//
#include <hip/hip_runtime.h>
#include <math.h>

#define NSITE 100
#define NOCC  50
#define DIM   128
#define KDET  4

// ---------------------------------------------------------------------------
// Wave64 max-reduction via DPP (VALU-only, ~30 cyc dependent chain) instead
// of 6 ds_swizzle round-trips (~240 cyc). Canonical gfx9 sequence:
// row_shr 1/2/4/8 (max within each 16-lane row into lane 15 of the row),
// bcast15 (lane15->16..31, lane47->48..63, row_mask 0xa),
// bcast31 (lane31->32..63, row_mask 0xc). Lane 63 ends with the global max.
// bound_ctrl=false + old=x -> invalid lanes keep x, max() is unaffected.
// ---------------------------------------------------------------------------
__device__ __forceinline__ unsigned dpp_max64_to_lane63(unsigned x) {
  unsigned t;
  t = (unsigned)__builtin_amdgcn_update_dpp((int)x, (int)x, 0x111, 0xf, 0xf, false);
  x = x > t ? x : t;   // row_shr:1
  t = (unsigned)__builtin_amdgcn_update_dpp((int)x, (int)x, 0x112, 0xf, 0xf, false);
  x = x > t ? x : t;   // row_shr:2
  t = (unsigned)__builtin_amdgcn_update_dpp((int)x, (int)x, 0x114, 0xf, 0xf, false);
  x = x > t ? x : t;   // row_shr:4
  t = (unsigned)__builtin_amdgcn_update_dpp((int)x, (int)x, 0x118, 0xf, 0xf, false);
  x = x > t ? x : t;   // row_shr:8
  t = (unsigned)__builtin_amdgcn_update_dpp((int)x, (int)x, 0x142, 0xa, 0xf, false);
  x = x > t ? x : t;   // row_bcast15
  t = (unsigned)__builtin_amdgcn_update_dpp((int)x, (int)x, 0x143, 0xc, 0xf, false);
  x = x > t ? x : t;   // row_bcast31
  return x;
}

// ---------------------------------------------------------------------------
// R10-R12 register-allocator frontier (measured):
//   (4,4):  VGPR=52 spill-free, 4 waves/EU, 622us  (latency-bound)
//   none:   VGPR=36 spills,    ~8 waves/EU, 602us
//   (8):    VGPR=32 heavy spill (44MB HBM scratch writes), 80% occ, 484us
// Demand is ~52-70 regs -> waves_per_eu(6) budget = 85: spill-free AND
// 6 waves/EU. min is the knob that bites (R8/R12 evidence).
// ---------------------------------------------------------------------------
#define REPA(X) X(0) X(1) X(2) X(3) X(4) X(5) X(6) X(7) X(8) X(9) \
  X(10) X(11) X(12) X(13) X(14) X(15) X(16) X(17) X(18) X(19) \
  X(20) X(21) X(22) X(23) X(24) X(25) X(26) X(27) X(28) X(29) \
  X(30) X(31) X(32) X(33) X(34) X(35) X(36) X(37) X(38) X(39) \
  X(40) X(41) X(42) X(43) X(44) X(45) X(46) X(47) X(48) X(49)
#define REPB(X) X(0) X(1) X(2) X(3) X(4) X(5) X(6) X(7) X(8) X(9) \
  X(10) X(11) X(12) X(13) X(14) X(15) X(16) X(17) X(18) X(19) \
  X(20) X(21) X(22) X(23) X(24) X(25) X(26) X(27) X(28) X(29) \
  X(30) X(31) X(32) X(33) X(34) X(35) X(36) X(37) X(38) X(39) \
  X(40) X(41) X(42) X(43) X(44) X(45) X(46) X(47) X(48) X(49)

// One block per (batch, spin). Wave w handles determinant k=w.
// Lane r owns row r of phi in 50 named fp32 registers (r < 50).
__global__ __launch_bounds__(256)
__attribute__((amdgpu_waves_per_eu(6)))
void det_kernel(
    const int*   __restrict__ configs,   // (B,100) int32
    const float* __restrict__ tok,       // (4,128)
    const float* __restrict__ pos,       // (144,128)
    const float* __restrict__ W,         // (400,128)
    const float* __restrict__ bvec,      // (400,)
    double*      __restrict__ dets)      // (B,2,4,2)  {logdet, sign}
{
  const int b    = blockIdx.x;
  const int spin = blockIdx.y;

  __shared__ int cfg[NSITE];
  __shared__ int idx[NOCC];
  __shared__ int occl[NOCC];
  __shared__ int filll[NOCC];
  __shared__ int perm[4][NOCC];

  const int tid = threadIdx.x;
  if (tid < NSITE) cfg[tid] = configs[(size_t)b * NSITE + tid];
  __syncthreads();

  // Occupied-index list per reference argsort semantics: all occupied sites
  // (ascending, capped 50) + smallest unoccupied fill, merged sorted.
  if (tid == 0) {
    int no = 0, nf = 0;
    for (int n = 0; n < NSITE; ++n) {
      int c = cfg[n];
      bool occ = (spin == 0) ? (c == 1 || c == 3) : (c == 2 || c == 3);
      if (occ) { if (no < NOCC) occl[no++]  = n; }
      else     { if (nf < NOCC) filll[nf++] = n; }
    }
    int need = NOCC - no; if (need < 0) need = 0;
    int i = 0, j = 0;
    for (int k = 0; k < NOCC; ++k) {
      bool takeocc = (i < no) && (j >= need || occl[i] < filll[j]);
      idx[k] = takeocc ? occl[i++] : filll[j++];
    }
  }
  __syncthreads();

  const int lane = tid & 63;
  const int wave = tid >> 6;
  const int wave_u  = __builtin_amdgcn_readfirstlane(wave);
  const int colbase = spin * 200 + wave_u * 50;          // uniform
  const float* Wb = W    + (size_t)colbase * DIM;        // uniform base
  const float* bb = bvec + colbase;

  const bool act  = (lane < NOCC);
  const int  site = idx[act ? lane : 0];
  const int  cc0  = cfg[site];
  const float4* tok4 = (const float4*)(tok + (size_t)cc0  * DIM);
  const float4* pos4 = (const float4*)(pos + (size_t)site * DIM);
  const float4* W4   = (const float4*)Wb;

  // ---- GEMM (fp32): q0..q49 = h . W[colbase + 0..49] + b ----
  #define DECLQ(i) float q##i = bb[i];
  REPB(DECLQ)
  #undef DECLQ

  for (int d4 = 0; d4 < DIM / 4; ++d4) {
    float4 t = tok4[d4], pv = pos4[d4];
    const float h0 = t.x + pv.x, h1 = t.y + pv.y;
    const float h2 = t.z + pv.z, h3 = t.w + pv.w;
    #define GSTEP(i) { float4 w = W4[(i) * (DIM / 4) + d4]; \
      q##i = fmaf(h3, w.w, fmaf(h2, w.z, fmaf(h1, w.y, fmaf(h0, w.x, q##i)))); }
    REPB(GSTEP)
    #undef GSTEP
  }

  // zero inactive lanes so they never win the pivot and updates stay benign
  #define ZEROQ(i) q##i = act ? q##i : 0.0f;
  REPB(ZEROQ)
  #undef ZEROQ

  // ---- LU (fp32, in place on q) with implicit partial pivoting ----------
  float  mant_prod = 1.0f;     // product of pivot mantissas in [1,2): < 2^50
  int    esum = 0, neg = 0, mystep = -1;
  unsigned alive = act ? 1u : 0u;

  #define UPD(CC) if ((CC) > cJ) { \
      const float pc = __int_as_float( \
          __builtin_amdgcn_readlane(__float_as_int(q##CC), p)); \
      q##CC = fmaf(-mult, pc, q##CC); }
  #define LUS(J) { \
    const unsigned ab = __float_as_uint(q##J) & 0x7FFFFFFFu; \
    unsigned key = alive ? ((ab & ~63u) | (unsigned)lane) : 0u; \
    key = dpp_max64_to_lane63(key); \
    const int p = __builtin_amdgcn_readlane((int)key, 63) & 63; \
    const float piv = __int_as_float( \
        __builtin_amdgcn_readlane(__float_as_int(q##J), p)); \
    const unsigned pb = __float_as_uint(piv); \
    esum += (int)((pb >> 23) & 0xFFu) - 127; \
    neg  += (int)(pb >> 31); \
    mant_prod *= __uint_as_float((pb & 0x007FFFFFu) | 0x3F800000u); \
    if (lane == p) mystep = (J); \
    alive &= (lane != p) ? 1u : 0u; \
    const float rp = (piv != 0.0f) ? 1.0f / piv : 0.0f; \
    const float mult = alive ? q##J * rp : 0.0f; \
    const int cJ = (J); \
    REPB(UPD) \
  }
  REPA(LUS)
  #undef LUS
  #undef UPD

  const double logdet =
      log((double)mant_prod) + (double)esum * 0.6931471805599453;

  // permutation parity: perm[step] = lane chosen at that step (LDS)
  if (mystep >= 0) perm[wave][mystep] = lane;
  __syncthreads();
  int pj  = perm[wave][act ? lane : 0];
  int inv = 0;
  for (int i = 0; i < NOCC; ++i) {
    int pi = perm[wave][i];
    inv += (act && i < lane && pi > pj) ? 1 : 0;
  }
  #pragma unroll
  for (int m = 32; m >= 1; m >>= 1) inv += __shfl_xor(inv, m, 64);

  const int sgn = ((neg + inv) & 1) ? -1 : 1;
  if (lane == 0) {
    size_t o = (((size_t)b * 2 + spin) * KDET + wave) * 2;
    dets[o]     = logdet;
    dets[o + 1] = (double)sgn;
  }
}

// PLANAR complex64 output: out[0..B) = log_abs (real), out[B..2B) = phase (imag)
__global__ __launch_bounds__(256) void combine_kernel(
    const double* __restrict__ dets, float* __restrict__ out, int B)
{
  int b = blockIdx.x * blockDim.x + threadIdx.x;
  if (b >= B) return;
  const double* du = dets + ((size_t)b * 2 + 0) * KDET * 2;
  const double* dd = dets + ((size_t)b * 2 + 1) * KDET * 2;
  double t[KDET], s[KDET], m = -1e300;
  #pragma unroll
  for (int k = 0; k < KDET; ++k) {
    t[k] = du[2 * k] + dd[2 * k];
    s[k] = du[2 * k + 1] * dd[2 * k + 1];
    if (t[k] > m) m = t[k];
  }
  double sum = 0.0;
  #pragma unroll
  for (int k = 0; k < KDET; ++k) {
    if (t[k] > -1e290) sum += s[k] * exp(t[k] - m);
  }
  double p  = (m > -1e290) ? exp(m) * fabs(sum) : 0.0;
  double la = log(p + 1e-30);                    // reproduce ref clamp exactly
  float phase = (sum >= 0.0) ? 0.0f : 3.14159265358979f;
  out[b]     = (float)la;
  out[B + b] = phase;
}

extern "C" void kernel_launch(void* const* d_in, const int* in_sizes, int n_in,
                              void* d_out, int out_size, void* d_ws, size_t ws_size,
                              hipStream_t stream) {
  const int*   configs = (const int*)  d_in[0];
  const float* tok     = (const float*)d_in[1];
  const float* pos     = (const float*)d_in[2];
  const float* W       = (const float*)d_in[3];
  const float* bv      = (const float*)d_in[4];
  double* dets = (double*)d_ws;            // needs B*2*4*2*8 = 256 KB
  const int B = in_sizes[0] / NSITE;

  dim3 grid(B, 2);
  det_kernel<<<grid, 256, 0, stream>>>(configs, tok, pos, W, bv, dets);
  combine_kernel<<<(B + 255) / 256, 256, 0, stream>>>(dets, (float*)d_out, B);
}

// Round 14
// 461.958 us; speedup vs baseline: 1.3088x; 1.3088x over previous
//
#include <hip/hip_runtime.h>
#include <math.h>

#define NSITE 100
#define NOCC  50
#define DIM   128
#define KDET  4

// ---------------------------------------------------------------------------
// Wave64 max-reduction via DPP (VALU-only) instead of ds_swizzle round-trips.
// row_shr 1/2/4/8 + row_bcast15 + row_bcast31; lane 63 ends with global max.
// ---------------------------------------------------------------------------
__device__ __forceinline__ unsigned dpp_max64_to_lane63(unsigned x) {
  unsigned t;
  t = (unsigned)__builtin_amdgcn_update_dpp((int)x, (int)x, 0x111, 0xf, 0xf, false);
  x = x > t ? x : t;   // row_shr:1
  t = (unsigned)__builtin_amdgcn_update_dpp((int)x, (int)x, 0x112, 0xf, 0xf, false);
  x = x > t ? x : t;   // row_shr:2
  t = (unsigned)__builtin_amdgcn_update_dpp((int)x, (int)x, 0x114, 0xf, 0xf, false);
  x = x > t ? x : t;   // row_shr:4
  t = (unsigned)__builtin_amdgcn_update_dpp((int)x, (int)x, 0x118, 0xf, 0xf, false);
  x = x > t ? x : t;   // row_shr:8
  t = (unsigned)__builtin_amdgcn_update_dpp((int)x, (int)x, 0x142, 0xa, 0xf, false);
  x = x > t ? x : t;   // row_bcast15
  t = (unsigned)__builtin_amdgcn_update_dpp((int)x, (int)x, 0x143, 0xc, 0xf, false);
  x = x > t ? x : t;   // row_bcast31
  return x;
}

// ---------------------------------------------------------------------------
// R10-R13 frontier: TLP beats spill cost -- wall time tracked occupancy
// ((4,4)/52reg/44%=622us, (6)/40reg/61%=605us, (8)/32reg/80%=484us).
// The ideal point (spill-free AND 8 waves/EU) needs peak demand <=64.
// LU needs ~56; the single-pass GEMM peaked ~70 (50 q + 16 transients),
// forcing the min=8 RA to spill 20 q regs (44MB scratch churn).
// Fix: TWO 25-column GEMM sweeps -- peak = 25 done + 25 building + ~12
// transients = ~62 < 64. Costs 64 redundant L1-hot tok/pos loads.
// ---------------------------------------------------------------------------
#define REPA(X) X(0) X(1) X(2) X(3) X(4) X(5) X(6) X(7) X(8) X(9) \
  X(10) X(11) X(12) X(13) X(14) X(15) X(16) X(17) X(18) X(19) \
  X(20) X(21) X(22) X(23) X(24) X(25) X(26) X(27) X(28) X(29) \
  X(30) X(31) X(32) X(33) X(34) X(35) X(36) X(37) X(38) X(39) \
  X(40) X(41) X(42) X(43) X(44) X(45) X(46) X(47) X(48) X(49)
#define REPB(X) X(0) X(1) X(2) X(3) X(4) X(5) X(6) X(7) X(8) X(9) \
  X(10) X(11) X(12) X(13) X(14) X(15) X(16) X(17) X(18) X(19) \
  X(20) X(21) X(22) X(23) X(24) X(25) X(26) X(27) X(28) X(29) \
  X(30) X(31) X(32) X(33) X(34) X(35) X(36) X(37) X(38) X(39) \
  X(40) X(41) X(42) X(43) X(44) X(45) X(46) X(47) X(48) X(49)
#define REPL(X) X(0) X(1) X(2) X(3) X(4) X(5) X(6) X(7) X(8) X(9) \
  X(10) X(11) X(12) X(13) X(14) X(15) X(16) X(17) X(18) X(19) \
  X(20) X(21) X(22) X(23) X(24)
#define REPH(X) X(25) X(26) X(27) X(28) X(29) \
  X(30) X(31) X(32) X(33) X(34) X(35) X(36) X(37) X(38) X(39) \
  X(40) X(41) X(42) X(43) X(44) X(45) X(46) X(47) X(48) X(49)

// One block per (batch, spin). Wave w handles determinant k=w.
// Lane r owns row r of phi in 50 named fp32 registers (r < 50).
__global__ __launch_bounds__(256)
__attribute__((amdgpu_waves_per_eu(8)))
void det_kernel(
    const int*   __restrict__ configs,   // (B,100) int32
    const float* __restrict__ tok,       // (4,128)
    const float* __restrict__ pos,       // (144,128)
    const float* __restrict__ W,         // (400,128)
    const float* __restrict__ bvec,      // (400,)
    double*      __restrict__ dets)      // (B,2,4,2)  {logdet, sign}
{
  const int b    = blockIdx.x;
  const int spin = blockIdx.y;

  __shared__ int cfg[NSITE];
  __shared__ int idx[NOCC];
  __shared__ int occl[NOCC];
  __shared__ int filll[NOCC];
  __shared__ int perm[4][NOCC];

  const int tid = threadIdx.x;
  if (tid < NSITE) cfg[tid] = configs[(size_t)b * NSITE + tid];
  __syncthreads();

  // Occupied-index list per reference argsort semantics: all occupied sites
  // (ascending, capped 50) + smallest unoccupied fill, merged sorted.
  if (tid == 0) {
    int no = 0, nf = 0;
    for (int n = 0; n < NSITE; ++n) {
      int c = cfg[n];
      bool occ = (spin == 0) ? (c == 1 || c == 3) : (c == 2 || c == 3);
      if (occ) { if (no < NOCC) occl[no++]  = n; }
      else     { if (nf < NOCC) filll[nf++] = n; }
    }
    int need = NOCC - no; if (need < 0) need = 0;
    int i = 0, j = 0;
    for (int k = 0; k < NOCC; ++k) {
      bool takeocc = (i < no) && (j >= need || occl[i] < filll[j]);
      idx[k] = takeocc ? occl[i++] : filll[j++];
    }
  }
  __syncthreads();

  const int lane = tid & 63;
  const int wave = tid >> 6;
  const int wave_u  = __builtin_amdgcn_readfirstlane(wave);
  const int colbase = spin * 200 + wave_u * 50;          // uniform
  const float* Wb = W    + (size_t)colbase * DIM;        // uniform base
  const float* bb = bvec + colbase;

  const bool act  = (lane < NOCC);
  const int  site = idx[act ? lane : 0];
  const int  cc0  = cfg[site];
  const float4* tok4 = (const float4*)(tok + (size_t)cc0  * DIM);
  const float4* pos4 = (const float4*)(pos + (size_t)site * DIM);
  const float4* W4   = (const float4*)Wb;

  #define GSTEP(i) { float4 w = W4[(i) * (DIM / 4) + d4]; \
    q##i = fmaf(h3, w.w, fmaf(h2, w.z, fmaf(h1, w.y, fmaf(h0, w.x, q##i)))); }
  #define DECLQ(i) float q##i = bb[i];

  // ---- GEMM sweep 1 (fp32): q0..q24 ----
  REPL(DECLQ)
  for (int d4 = 0; d4 < DIM / 4; ++d4) {
    float4 t = tok4[d4], pv = pos4[d4];
    const float h0 = t.x + pv.x, h1 = t.y + pv.y;
    const float h2 = t.z + pv.z, h3 = t.w + pv.w;
    REPL(GSTEP)
  }

  // ---- GEMM sweep 2 (fp32): q25..q49 (tok/pos re-reads are L1-hot) ----
  REPH(DECLQ)
  for (int d4 = 0; d4 < DIM / 4; ++d4) {
    float4 t = tok4[d4], pv = pos4[d4];
    const float h0 = t.x + pv.x, h1 = t.y + pv.y;
    const float h2 = t.z + pv.z, h3 = t.w + pv.w;
    REPH(GSTEP)
  }
  #undef DECLQ
  #undef GSTEP

  // zero inactive lanes so they never win the pivot and updates stay benign
  #define ZEROQ(i) q##i = act ? q##i : 0.0f;
  REPB(ZEROQ)
  #undef ZEROQ

  // ---- LU (fp32, in place on q) with implicit partial pivoting ----------
  float  mant_prod = 1.0f;     // product of pivot mantissas in [1,2): < 2^50
  int    esum = 0, neg = 0, mystep = -1;
  unsigned alive = act ? 1u : 0u;

  #define UPD(CC) if ((CC) > cJ) { \
      const float pc = __int_as_float( \
          __builtin_amdgcn_readlane(__float_as_int(q##CC), p)); \
      q##CC = fmaf(-mult, pc, q##CC); }
  #define LUS(J) { \
    const unsigned ab = __float_as_uint(q##J) & 0x7FFFFFFFu; \
    unsigned key = alive ? ((ab & ~63u) | (unsigned)lane) : 0u; \
    key = dpp_max64_to_lane63(key); \
    const int p = __builtin_amdgcn_readlane((int)key, 63) & 63; \
    const float piv = __int_as_float( \
        __builtin_amdgcn_readlane(__float_as_int(q##J), p)); \
    const unsigned pb = __float_as_uint(piv); \
    esum += (int)((pb >> 23) & 0xFFu) - 127; \
    neg  += (int)(pb >> 31); \
    mant_prod *= __uint_as_float((pb & 0x007FFFFFu) | 0x3F800000u); \
    if (lane == p) mystep = (J); \
    alive &= (lane != p) ? 1u : 0u; \
    const float rp = (piv != 0.0f) ? 1.0f / piv : 0.0f; \
    const float mult = alive ? q##J * rp : 0.0f; \
    const int cJ = (J); \
    REPB(UPD) \
  }
  REPA(LUS)
  #undef LUS
  #undef UPD

  const double logdet =
      log((double)mant_prod) + (double)esum * 0.6931471805599453;

  // permutation parity: perm[step] = lane chosen at that step (LDS)
  if (mystep >= 0) perm[wave][mystep] = lane;
  __syncthreads();
  int pj  = perm[wave][act ? lane : 0];
  int inv = 0;
  for (int i = 0; i < NOCC; ++i) {
    int pi = perm[wave][i];
    inv += (act && i < lane && pi > pj) ? 1 : 0;
  }
  #pragma unroll
  for (int m = 32; m >= 1; m >>= 1) inv += __shfl_xor(inv, m, 64);

  const int sgn = ((neg + inv) & 1) ? -1 : 1;
  if (lane == 0) {
    size_t o = (((size_t)b * 2 + spin) * KDET + wave) * 2;
    dets[o]     = logdet;
    dets[o + 1] = (double)sgn;
  }
}

// PLANAR complex64 output: out[0..B) = log_abs (real), out[B..2B) = phase (imag)
__global__ __launch_bounds__(256) void combine_kernel(
    const double* __restrict__ dets, float* __restrict__ out, int B)
{
  int b = blockIdx.x * blockDim.x + threadIdx.x;
  if (b >= B) return;
  const double* du = dets + ((size_t)b * 2 + 0) * KDET * 2;
  const double* dd = dets + ((size_t)b * 2 + 1) * KDET * 2;
  double t[KDET], s[KDET], m = -1e300;
  #pragma unroll
  for (int k = 0; k < KDET; ++k) {
    t[k] = du[2 * k] + dd[2 * k];
    s[k] = du[2 * k + 1] * dd[2 * k + 1];
    if (t[k] > m) m = t[k];
  }
  double sum = 0.0;
  #pragma unroll
  for (int k = 0; k < KDET; ++k) {
    if (t[k] > -1e290) sum += s[k] * exp(t[k] - m);
  }
  double p  = (m > -1e290) ? exp(m) * fabs(sum) : 0.0;
  double la = log(p + 1e-30);                    // reproduce ref clamp exactly
  float phase = (sum >= 0.0) ? 0.0f : 3.14159265358979f;
  out[b]     = (float)la;
  out[B + b] = phase;
}

extern "C" void kernel_launch(void* const* d_in, const int* in_sizes, int n_in,
                              void* d_out, int out_size, void* d_ws, size_t ws_size,
                              hipStream_t stream) {
  const int*   configs = (const int*)  d_in[0];
  const float* tok     = (const float*)d_in[1];
  const float* pos     = (const float*)d_in[2];
  const float* W       = (const float*)d_in[3];
  const float* bv      = (const float*)d_in[4];
  double* dets = (double*)d_ws;            // needs B*2*4*2*8 = 256 KB
  const int B = in_sizes[0] / NSITE;

  dim3 grid(B, 2);
  det_kernel<<<grid, 256, 0, stream>>>(configs, tok, pos, W, bv, dets);
  combine_kernel<<<(B + 255) / 256, 256, 0, stream>>>(dets, (float*)d_out, B);
}